// Round 9
// baseline (179.884 us; speedup 1.0000x reference)
//
#include <hip/hip_runtime.h>
#include <math.h>

// CascadeGCN: 2-layer GCN, N=100000, E=2.5M, 5 -> 32 -> 1.
// R9 = R5 (best measured, 162.8us) + two occupancy fixes:
//  - k_part stages a 2B permutation index instead of 4B records + 2B bucket
//    ids (LDS 61->23 KB); writeout re-gathers src/dst from the hot chunk
//    window (L1/L2).
//  - k_sortb reads pairs twice from global instead of staging (LDS 68->33 KB),
//    512 threads.
// Pipeline: init -> part -> sortb -> agg1 -> agg2.  (R8 lesson: cooperative
// launch fails silently on this harness — stay with plain launches.)

#define NB_SHIFT  8          // 256 nodes per bucket
#define BNODES    256
#define NBK       512        // level-1 key space (nb = 391, padded)
#define CAP       8192       // bucket capacity (mean 6400, +22 sigma)
#define CAP_SHIFT 13
#define CHUNK     8192
#define PBLK      256

// ---- init fixed-capacity bucket cursors ----
__global__ void k_init(int* __restrict__ bcur) {
    int b = threadIdx.x;
    if (b < NBK) bcur[b] = b << CAP_SHIFT;
}

// ---- bucket partition, ushort-perm staging; packed 4 B records ----
__global__ __launch_bounds__(PBLK) void k_part(const int* __restrict__ src,
                                               const int* __restrict__ dst, int E,
                                               int* __restrict__ bcur,
                                               int* __restrict__ pairs) {
    __shared__ unsigned short perm[CHUNK];    // 16 KB: slot -> chunk-local idx
    __shared__ int cnt[NBK], cur[NBK], gbase[NBK];   // 6 KB
    __shared__ int tsum[PBLK];                // 1 KB
    int tid = threadIdx.x;
    int base = blockIdx.x * CHUNK;
    int m = min(CHUNK, E - base);

    for (int b = tid; b < NBK; b += PBLK) cnt[b] = 0;
    __syncthreads();
    // pass 1: histogram (dst read #1, coalesced)
    for (int i = tid; i < m; i += PBLK)
        atomicAdd(&cnt[dst[base + i] >> NB_SHIFT], 1);
    __syncthreads();
    // exclusive scan of cnt: each thread owns 2 consecutive buckets
    int b0 = tid * 2;
    int s0 = cnt[b0], s1 = cnt[b0 + 1], tot = s0 + s1;
    tsum[tid] = tot;
    __syncthreads();
    for (int off = 1; off < PBLK; off <<= 1) {
        int u = (tid >= off) ? tsum[tid - off] : 0;
        __syncthreads();
        tsum[tid] += u;
        __syncthreads();
    }
    int pre = tsum[tid] - tot;
    cur[b0] = pre;      cur[b0 + 1] = pre + s0;
    gbase[b0]     = s0 ? atomicAdd(&bcur[b0], s0) : 0;
    gbase[b0 + 1] = s1 ? atomicAdd(&bcur[b0 + 1], s1) : 0;
    __syncthreads();
    // pass 2: bucket-ordered permutation into LDS (dst read #2, L1/L2-hot)
    for (int i = tid; i < m; i += PBLK) {
        int b = dst[base + i] >> NB_SHIFT;
        int p = atomicAdd(&cur[b], 1);
        perm[p] = (unsigned short)i;
    }
    __syncthreads();
    // writeout: re-gather src/dst through perm (window is L1/L2-resident);
    // start of run b = cur[b] - cnt[b]
    for (int i = tid; i < m; i += PBLK) {
        int j = perm[i];
        int s = src[base + j], d = dst[base + j];
        int b = d >> NB_SHIFT;
        int start = cur[b] - cnt[b];
        pairs[gbase[b] + (i - start)] = ((d & (BNODES - 1)) << 24) | s;
    }
}

// ---- per-bucket counting sort by node (LDS) + dinv/nofs/deg/xs prep ----
__global__ __launch_bounds__(512) void k_sortb(int* __restrict__ pairs,
                                               const int* __restrict__ bcur,
                                               const float* __restrict__ x,
                                               float* __restrict__ dinv,
                                               float* __restrict__ xs,
                                               int* __restrict__ nofs,
                                               int* __restrict__ deg, int n) {
    __shared__ int stage2[CAP];               // 32 KB
    __shared__ int cnt[BNODES], cur[BNODES], scn[BNODES];   // 3 KB
    int tid = threadIdx.x;
    int b = blockIdx.x;
    int base = b << CAP_SHIFT;
    int len = min(bcur[b] - base, CAP);

    if (tid < BNODES) cnt[tid] = 0;
    __syncthreads();
    // global read #1: histogram of node-low-byte (coalesced)
    for (int i = tid; i < len; i += 512)
        atomicAdd(&cnt[((unsigned)pairs[base + i]) >> 24], 1);
    __syncthreads();
    int v = (tid < BNODES) ? cnt[tid] : 0;
    if (tid < BNODES) scn[tid] = v;
    __syncthreads();
    for (int off = 1; off < BNODES; off <<= 1) {   // Hillis-Steele inclusive
        int u = (tid < BNODES && tid >= off) ? scn[tid - off] : 0;
        __syncthreads();
        if (tid < BNODES) scn[tid] += u;
        __syncthreads();
    }
    if (tid < BNODES) {
        int pos = scn[tid] - v;                    // exclusive
        cur[tid] = pos;
        int node = (b << NB_SHIFT) + tid;
        if (node < n) {
            nofs[node] = base + pos;
            deg[node] = v;
            float di = rsqrtf((float)v + 1.0f);
            dinv[node] = di;
            const float* xr = x + (size_t)node * 5;
            float* xo = xs + ((size_t)node << 3);  // padded row: 8 floats
#pragma unroll
            for (int k = 0; k < 5; ++k) xo[k] = xr[k] * di;
        }
    }
    __syncthreads();
    // global read #2: counting-sort scatter into LDS
    for (int i = tid; i < len; i += 512) {
        int vv = pairs[base + i];
        int p = atomicAdd(&cur[((unsigned)vv) >> 24], 1);
        stage2[p] = vv & 0x00FFFFFF;               // src only
    }
    __syncthreads();
    for (int i = tid; i < len; i += 512) pairs[base + i] = stage2[i];
}

// ---- layer-1: register accumulation over per-node run + fused W1/relu/W2 ----
__global__ __launch_bounds__(256) void k_agg1(const int* __restrict__ pairs,
                                              const int* __restrict__ nofs,
                                              const int* __restrict__ deg,
                                              const float* __restrict__ xs,
                                              const float* __restrict__ dinv,
                                              const float* __restrict__ W1,
                                              const float* __restrict__ b1,
                                              const float* __restrict__ W2,
                                              float* __restrict__ h2s, int n) {
    __shared__ float w1[160], bb1[32], w2[32];
    int tid = threadIdx.x;
    if (tid < 160) w1[tid] = W1[tid];
    else if (tid < 192) bb1[tid - 160] = b1[tid - 160];
    else if (tid < 224) w2[tid - 192] = W2[tid - 192];
    __syncthreads();
    int node = blockIdx.x * 128 + (tid >> 1);
    int half = tid & 1;
    if (node >= n) return;
    int beg = nofs[node], dg = deg[node];
    float a0 = 0.f, a1 = 0.f, a2 = 0.f, a3 = 0.f, a4 = 0.f;
    if (!half) {                                   // self-loop term
        const float* xo = xs + ((size_t)node << 3);
        a0 = xo[0]; a1 = xo[1]; a2 = xo[2]; a3 = xo[3]; a4 = xo[4];
    }
    for (int e = beg + half; e < beg + dg; e += 2) {
        int s = pairs[e];
        const float* xr = xs + ((size_t)s << 3);
        float4 q = *(const float4*)xr;
        float q4 = xr[4];
        a0 += q.x; a1 += q.y; a2 += q.z; a3 += q.w; a4 += q4;
    }
    a0 += __shfl_xor(a0, 1); a1 += __shfl_xor(a1, 1); a2 += __shfl_xor(a2, 1);
    a3 += __shfl_xor(a3, 1); a4 += __shfl_xor(a4, 1);
    if (half) return;
    float di = dinv[node];
    a0 *= di; a1 *= di; a2 *= di; a3 *= di; a4 *= di;
    float sum = 0.f;
#pragma unroll
    for (int c = 0; c < 32; ++c) {
        float z = bb1[c] + a0 * w1[c] + a1 * w1[32 + c] + a2 * w1[64 + c]
                         + a3 * w1[96 + c] + a4 * w1[128 + c];
        sum += fmaxf(z, 0.f) * w2[c];
    }
    h2s[node] = sum * di;                          // pre-scale by source dinv
}

// ---- layer-2: register accumulation + sigmoid ----
__global__ __launch_bounds__(256) void k_agg2(const int* __restrict__ pairs,
                                              const int* __restrict__ nofs,
                                              const int* __restrict__ deg,
                                              const float* __restrict__ h2s,
                                              const float* __restrict__ dinv,
                                              const float* __restrict__ b2,
                                              float* __restrict__ out, int n) {
    int tid = threadIdx.x;
    int node = blockIdx.x * 128 + (tid >> 1);
    int half = tid & 1;
    if (node >= n) return;
    int beg = nofs[node], dg = deg[node];
    float a = 0.f;
    for (int e = beg + half; e < beg + dg; e += 2) a += h2s[pairs[e]];
    a += __shfl_xor(a, 1);
    if (half) return;
    float v = dinv[node] * (a + h2s[node]) + b2[0];
    out[node] = 1.0f / (1.0f + __expf(-v));
}

extern "C" void kernel_launch(void* const* d_in, const int* in_sizes, int n_in,
                              void* d_out, int out_size, void* d_ws, size_t ws_size,
                              hipStream_t stream) {
    const float* x  = (const float*)d_in[0];
    const int*   ei = (const int*)d_in[1];
    const float* W1 = (const float*)d_in[2];
    const float* b1 = (const float*)d_in[3];
    const float* W2 = (const float*)d_in[4];
    const float* b2 = (const float*)d_in[5];
    float* out = (float*)d_out;

    const int n = in_sizes[0] / 5;       // 100000
    const int E = in_sizes[1] / 2;       // 2500000
    const int* src = ei;
    const int* dst = ei + E;
    const int nb = (n + BNODES - 1) >> NB_SHIFT;   // 391

    // ws (4B units, 16B-aligned):
    // [pairs (nb+1)<<13][nofs n][deg n][dinv n][h2s n][xs 8n][bcur NBK]
    int* wsi = (int*)d_ws;
    int*   pairs = wsi;
    int*   nofs  = wsi + ((size_t)(nb + 1) << CAP_SHIFT);
    int*   deg   = nofs + n;
    float* dinv  = (float*)(deg + n);
    float* h2s   = dinv + n;
    float* xs    = h2s + n;
    int*   bcur  = (int*)(xs + (size_t)8 * n);

    const int nchunk = (E + CHUNK - 1) / CHUNK;    // 306
    const int nagg   = (n + 127) / 128;            // 782

    k_init<<<1, NBK, 0, stream>>>(bcur);
    k_part<<<nchunk, PBLK, 0, stream>>>(src, dst, E, bcur, pairs);
    k_sortb<<<nb, 512, 0, stream>>>(pairs, bcur, x, dinv, xs, nofs, deg, n);
    k_agg1<<<nagg, 256, 0, stream>>>(pairs, nofs, deg, xs, dinv, W1, b1, W2, h2s, n);
    k_agg2<<<nagg, 256, 0, stream>>>(pairs, nofs, deg, h2s, dinv, b2, out, n);
}

// Round 10
// 156.833 us; speedup vs baseline: 1.1470x; 1.1470x over previous
//
#include <hip/hip_runtime.h>
#include <math.h>

// CascadeGCN: 2-layer GCN, N=100000, E=2.5M, 5 -> 32 -> 1.
// R10 = R5 (best measured, 162.8us) with 512-thread k_part/k_sortb:
// k_part is grid-limited (306 blocks on 256 CU = 1.19 blocks/CU), so more
// waves per block is the only way to add latency hiding (R9 lesson: LDS
// dieting does nothing when occupancy is grid-bound).
// Pipeline: init -> part -> sortb -> agg1 -> agg2.

#define NB_SHIFT  8          // 256 nodes per bucket
#define BNODES    256
#define NBK       512        // level-1 key space (nb = 391, padded)
#define CAP       8192       // bucket capacity (mean 6400, +22 sigma)
#define CAP_SHIFT 13
#define CHUNK     8192
#define PBLK      512        // 8 waves

// ---- init fixed-capacity bucket cursors ----
__global__ void k_init(int* __restrict__ bcur) {
    int b = threadIdx.x;
    if (b < NBK) bcur[b] = b << CAP_SHIFT;
}

// ---- LDS-staged bucket partition; packed 4 B records (dlow<<24 | src) ----
__global__ __launch_bounds__(PBLK) void k_part(const int* __restrict__ src,
                                               const int* __restrict__ dst, int E,
                                               int* __restrict__ bcur,
                                               int* __restrict__ pairs) {
    __shared__ int sp[CHUNK];                 // 32 KB records
    __shared__ unsigned short sb[CHUNK];      // 16 KB bucket ids
    __shared__ int cnt[NBK], ofs[NBK], cur[NBK], gbase[NBK];  // 8 KB
    int tid = threadIdx.x;
    int base = blockIdx.x * CHUNK;
    int m = min(CHUNK, E - base);

    if (tid < NBK) cnt[tid] = 0;
    __syncthreads();
    // pass 1: histogram
    for (int i = tid; i < m; i += PBLK)
        atomicAdd(&cnt[dst[base + i] >> NB_SHIFT], 1);
    __syncthreads();
    // exclusive scan: one bucket per thread (PBLK == NBK), Hillis-Steele
    int v = cnt[tid];
    ofs[tid] = v;                             // reuse ofs as scan buffer
    __syncthreads();
    for (int off = 1; off < NBK; off <<= 1) {
        int u = (tid >= off) ? ofs[tid - off] : 0;
        __syncthreads();
        ofs[tid] += u;
        __syncthreads();
    }
    int pre = ofs[tid] - v;                   // exclusive prefix
    ofs[tid] = pre;
    cur[tid] = pre;
    gbase[tid] = v ? atomicAdd(&bcur[tid], v) : 0;
    __syncthreads();
    // pass 2: bucket-ordered scatter into LDS
    for (int i = tid; i < m; i += PBLK) {
        int s = src[base + i], d = dst[base + i];
        int b = d >> NB_SHIFT;
        int p = atomicAdd(&cur[b], 1);
        sp[p] = ((d & (BNODES - 1)) << 24) | s;
        sb[p] = (unsigned short)b;
    }
    __syncthreads();
    // coalesced-run writeout
    for (int i = tid; i < m; i += PBLK) {
        int b = sb[i];
        pairs[gbase[b] + (i - ofs[b])] = sp[i];
    }
}

// ---- per-bucket counting sort by node (LDS) + dinv/nofs/deg/xs prep ----
__global__ __launch_bounds__(512) void k_sortb(int* __restrict__ pairs,
                                               const int* __restrict__ bcur,
                                               const float* __restrict__ x,
                                               float* __restrict__ dinv,
                                               float* __restrict__ xs,
                                               int* __restrict__ nofs,
                                               int* __restrict__ deg, int n) {
    __shared__ int stage[CAP];                // 32 KB
    __shared__ int stage2[CAP];               // 32 KB
    __shared__ int cnt[BNODES], cur[BNODES], scn[BNODES];   // 3 KB
    int tid = threadIdx.x;
    int b = blockIdx.x;
    int base = b << CAP_SHIFT;
    int len = min(bcur[b] - base, CAP);

    for (int i = tid; i < len; i += 512) stage[i] = pairs[base + i];
    if (tid < BNODES) cnt[tid] = 0;
    __syncthreads();
    for (int i = tid; i < len; i += 512)
        atomicAdd(&cnt[((unsigned)stage[i]) >> 24], 1);
    __syncthreads();
    int v = (tid < BNODES) ? cnt[tid] : 0;
    if (tid < BNODES) scn[tid] = v;
    __syncthreads();
    for (int off = 1; off < BNODES; off <<= 1) {   // Hillis-Steele inclusive
        int u = (tid < BNODES && tid >= off) ? scn[tid - off] : 0;
        __syncthreads();
        if (tid < BNODES) scn[tid] += u;
        __syncthreads();
    }
    if (tid < BNODES) {
        int pos = scn[tid] - v;                    // exclusive
        cur[tid] = pos;
        int node = (b << NB_SHIFT) + tid;
        if (node < n) {
            nofs[node] = base + pos;
            deg[node] = v;
            float di = rsqrtf((float)v + 1.0f);
            dinv[node] = di;
            const float* xr = x + (size_t)node * 5;
            float* xo = xs + ((size_t)node << 3);  // padded row: 8 floats
#pragma unroll
            for (int k = 0; k < 5; ++k) xo[k] = xr[k] * di;
        }
    }
    __syncthreads();
    for (int i = tid; i < len; i += 512) {
        int vv = stage[i];
        int p = atomicAdd(&cur[((unsigned)vv) >> 24], 1);
        stage2[p] = vv & 0x00FFFFFF;               // src only
    }
    __syncthreads();
    for (int i = tid; i < len; i += 512) pairs[base + i] = stage2[i];
}

// ---- layer-1: register accumulation over per-node run + fused W1/relu/W2 ----
__global__ __launch_bounds__(256) void k_agg1(const int* __restrict__ pairs,
                                              const int* __restrict__ nofs,
                                              const int* __restrict__ deg,
                                              const float* __restrict__ xs,
                                              const float* __restrict__ dinv,
                                              const float* __restrict__ W1,
                                              const float* __restrict__ b1,
                                              const float* __restrict__ W2,
                                              float* __restrict__ h2s, int n) {
    __shared__ float w1[160], bb1[32], w2[32];
    int tid = threadIdx.x;
    if (tid < 160) w1[tid] = W1[tid];
    else if (tid < 192) bb1[tid - 160] = b1[tid - 160];
    else if (tid < 224) w2[tid - 192] = W2[tid - 192];
    __syncthreads();
    int node = blockIdx.x * 128 + (tid >> 1);
    int half = tid & 1;
    if (node >= n) return;
    int beg = nofs[node], dg = deg[node];
    float a0 = 0.f, a1 = 0.f, a2 = 0.f, a3 = 0.f, a4 = 0.f;
    if (!half) {                                   // self-loop term
        const float* xo = xs + ((size_t)node << 3);
        a0 = xo[0]; a1 = xo[1]; a2 = xo[2]; a3 = xo[3]; a4 = xo[4];
    }
    for (int e = beg + half; e < beg + dg; e += 2) {
        int s = pairs[e];
        const float* xr = xs + ((size_t)s << 3);
        float4 q = *(const float4*)xr;
        float q4 = xr[4];
        a0 += q.x; a1 += q.y; a2 += q.z; a3 += q.w; a4 += q4;
    }
    a0 += __shfl_xor(a0, 1); a1 += __shfl_xor(a1, 1); a2 += __shfl_xor(a2, 1);
    a3 += __shfl_xor(a3, 1); a4 += __shfl_xor(a4, 1);
    if (half) return;
    float di = dinv[node];
    a0 *= di; a1 *= di; a2 *= di; a3 *= di; a4 *= di;
    float sum = 0.f;
#pragma unroll
    for (int c = 0; c < 32; ++c) {
        float z = bb1[c] + a0 * w1[c] + a1 * w1[32 + c] + a2 * w1[64 + c]
                         + a3 * w1[96 + c] + a4 * w1[128 + c];
        sum += fmaxf(z, 0.f) * w2[c];
    }
    h2s[node] = sum * di;                          // pre-scale by source dinv
}

// ---- layer-2: register accumulation + sigmoid ----
__global__ __launch_bounds__(256) void k_agg2(const int* __restrict__ pairs,
                                              const int* __restrict__ nofs,
                                              const int* __restrict__ deg,
                                              const float* __restrict__ h2s,
                                              const float* __restrict__ dinv,
                                              const float* __restrict__ b2,
                                              float* __restrict__ out, int n) {
    int tid = threadIdx.x;
    int node = blockIdx.x * 128 + (tid >> 1);
    int half = tid & 1;
    if (node >= n) return;
    int beg = nofs[node], dg = deg[node];
    float a = 0.f;
    for (int e = beg + half; e < beg + dg; e += 2) a += h2s[pairs[e]];
    a += __shfl_xor(a, 1);
    if (half) return;
    float v = dinv[node] * (a + h2s[node]) + b2[0];
    out[node] = 1.0f / (1.0f + __expf(-v));
}

extern "C" void kernel_launch(void* const* d_in, const int* in_sizes, int n_in,
                              void* d_out, int out_size, void* d_ws, size_t ws_size,
                              hipStream_t stream) {
    const float* x  = (const float*)d_in[0];
    const int*   ei = (const int*)d_in[1];
    const float* W1 = (const float*)d_in[2];
    const float* b1 = (const float*)d_in[3];
    const float* W2 = (const float*)d_in[4];
    const float* b2 = (const float*)d_in[5];
    float* out = (float*)d_out;

    const int n = in_sizes[0] / 5;       // 100000
    const int E = in_sizes[1] / 2;       // 2500000
    const int* src = ei;
    const int* dst = ei + E;
    const int nb = (n + BNODES - 1) >> NB_SHIFT;   // 391

    // ws (4B units, 16B-aligned):
    // [pairs (nb+1)<<13][nofs n][deg n][dinv n][h2s n][xs 8n][bcur NBK]
    int* wsi = (int*)d_ws;
    int*   pairs = wsi;
    int*   nofs  = wsi + ((size_t)(nb + 1) << CAP_SHIFT);
    int*   deg   = nofs + n;
    float* dinv  = (float*)(deg + n);
    float* h2s   = dinv + n;
    float* xs    = h2s + n;
    int*   bcur  = (int*)(xs + (size_t)8 * n);

    const int nchunk = (E + CHUNK - 1) / CHUNK;    // 306
    const int nagg   = (n + 127) / 128;            // 782

    k_init<<<1, NBK, 0, stream>>>(bcur);
    k_part<<<nchunk, PBLK, 0, stream>>>(src, dst, E, bcur, pairs);
    k_sortb<<<nb, 512, 0, stream>>>(pairs, bcur, x, dinv, xs, nofs, deg, n);
    k_agg1<<<nagg, 256, 0, stream>>>(pairs, nofs, deg, xs, dinv, W1, b1, W2, h2s, n);
    k_agg2<<<nagg, 256, 0, stream>>>(pairs, nofs, deg, h2s, dinv, b2, out, n);
}

// Round 11
// 146.492 us; speedup vs baseline: 1.2279x; 1.0706x over previous
//
#include <hip/hip_runtime.h>
#include <math.h>

// CascadeGCN: 2-layer GCN, N=100000, E=2.5M, 5 -> 32 -> 1.
// R11 = R10 +
//  - k_part rechunked: CHUNK 8192->4888, grid 306->512 = exactly 2 blocks/CU
//    (no tail; 16 waves/CU; LDS 37.3 KB x2 co-resident).
//  - sortb split: k_sorta (hist -> deg/nofs/dinv/xs), k_sortagg1 (LDS counting
//    sort + layer-1 aggregation fused in one block, sorted writeback for agg2).
// Pipeline: init -> part -> sorta -> sortagg1 -> agg2.

#define NB_SHIFT  8          // 256 nodes per bucket
#define BNODES    256
#define NBK       512        // level-1 key space (nb = 391, padded)
#define CAP       8192       // bucket capacity (mean 6400, +22 sigma)
#define CAP_SHIFT 13
#define CHUNK     4888       // 512 chunks over E=2.5M
#define PBLK      512        // 8 waves

// ---- init fixed-capacity bucket cursors ----
__global__ void k_init(int* __restrict__ bcur) {
    int b = threadIdx.x;
    if (b < NBK) bcur[b] = b << CAP_SHIFT;
}

// ---- LDS-staged bucket partition; packed 4 B records (dlow<<24 | src) ----
__global__ __launch_bounds__(PBLK) void k_part(const int* __restrict__ src,
                                               const int* __restrict__ dst, int E,
                                               int* __restrict__ bcur,
                                               int* __restrict__ pairs) {
    __shared__ int sp[CHUNK];                 // 19.6 KB records
    __shared__ unsigned short sb[CHUNK];      // 9.8 KB bucket ids
    __shared__ int cnt[NBK], ofs[NBK], cur[NBK], gbase[NBK];  // 8 KB
    int tid = threadIdx.x;
    int base = blockIdx.x * CHUNK;
    int m = min(CHUNK, E - base);

    if (tid < NBK) cnt[tid] = 0;
    __syncthreads();
    // pass 1: histogram
    for (int i = tid; i < m; i += PBLK)
        atomicAdd(&cnt[dst[base + i] >> NB_SHIFT], 1);
    __syncthreads();
    // exclusive scan: one bucket per thread (PBLK == NBK), Hillis-Steele
    int v = cnt[tid];
    ofs[tid] = v;                             // reuse ofs as scan buffer
    __syncthreads();
    for (int off = 1; off < NBK; off <<= 1) {
        int u = (tid >= off) ? ofs[tid - off] : 0;
        __syncthreads();
        ofs[tid] += u;
        __syncthreads();
    }
    int pre = ofs[tid] - v;                   // exclusive prefix
    ofs[tid] = pre;
    cur[tid] = pre;
    gbase[tid] = v ? atomicAdd(&bcur[tid], v) : 0;
    __syncthreads();
    // pass 2: bucket-ordered scatter into LDS
    for (int i = tid; i < m; i += PBLK) {
        int s = src[base + i], d = dst[base + i];
        int b = d >> NB_SHIFT;
        int p = atomicAdd(&cur[b], 1);
        sp[p] = ((d & (BNODES - 1)) << 24) | s;
        sb[p] = (unsigned short)b;
    }
    __syncthreads();
    // coalesced-run writeout
    for (int i = tid; i < m; i += PBLK) {
        int b = sb[i];
        pairs[gbase[b] + (i - ofs[b])] = sp[i];
    }
}

// ---- per-bucket node histogram -> deg/nofs/dinv/xs ----
__global__ __launch_bounds__(512) void k_sorta(const int* __restrict__ pairs,
                                               const int* __restrict__ bcur,
                                               const float* __restrict__ x,
                                               float* __restrict__ dinv,
                                               float* __restrict__ xs,
                                               int* __restrict__ nofs,
                                               int* __restrict__ deg, int n) {
    __shared__ int cnt[BNODES], scn[BNODES];
    int tid = threadIdx.x;
    int b = blockIdx.x;
    int base = b << CAP_SHIFT;
    int len = min(bcur[b] - base, CAP);

    if (tid < BNODES) cnt[tid] = 0;
    __syncthreads();
    for (int i = tid; i < len; i += 512)
        atomicAdd(&cnt[((unsigned)pairs[base + i]) >> 24], 1);
    __syncthreads();
    int v = (tid < BNODES) ? cnt[tid] : 0;
    if (tid < BNODES) scn[tid] = v;
    __syncthreads();
    for (int off = 1; off < BNODES; off <<= 1) {   // Hillis-Steele inclusive
        int u = (tid < BNODES && tid >= off) ? scn[tid - off] : 0;
        __syncthreads();
        if (tid < BNODES) scn[tid] += u;
        __syncthreads();
    }
    if (tid < BNODES) {
        int node = (b << NB_SHIFT) + tid;
        if (node < n) {
            nofs[node] = base + scn[tid] - v;      // exclusive
            deg[node] = v;
            float di = rsqrtf((float)v + 1.0f);
            dinv[node] = di;
            const float* xr = x + (size_t)node * 5;
            float* xo = xs + ((size_t)node << 3);  // padded row: 8 floats
#pragma unroll
            for (int k = 0; k < 5; ++k) xo[k] = xr[k] * di;
        }
    }
}

// ---- LDS counting sort + fused layer-1 aggregation + sorted writeback ----
__global__ __launch_bounds__(512) void k_sortagg1(int* __restrict__ pairs,
                                                  const int* __restrict__ bcur,
                                                  const int* __restrict__ nofs,
                                                  const int* __restrict__ deg,
                                                  const float* __restrict__ xs,
                                                  const float* __restrict__ dinv,
                                                  const float* __restrict__ W1,
                                                  const float* __restrict__ b1,
                                                  const float* __restrict__ W2,
                                                  float* __restrict__ h2s, int n) {
    __shared__ int stage2[CAP];               // 32 KB: node-sorted src ids
    __shared__ int ofs[BNODES], cnt[BNODES], cur[BNODES];   // 3 KB
    __shared__ float w1[160], bb1[32], w2[32];
    int tid = threadIdx.x;
    int b = blockIdx.x;
    int nbase = b << NB_SHIFT;
    int base = b << CAP_SHIFT;
    int len = min(bcur[b] - base, CAP);

    if (tid < 160) w1[tid] = W1[tid];
    else if (tid < 192) bb1[tid - 160] = b1[tid - 160];
    else if (tid < 224) w2[tid - 192] = W2[tid - 192];
    if (tid < BNODES) {
        int node = nbase + tid;
        int o = 0, c = 0;
        if (node < n) { o = nofs[node] - base; c = deg[node]; }
        ofs[tid] = o; cnt[tid] = c; cur[tid] = o;
    }
    __syncthreads();
    // counting-sort scatter into LDS (keys with no edges never probed)
    for (int i = tid; i < len; i += 512) {
        int vv = pairs[base + i];
        int p = atomicAdd(&cur[((unsigned)vv) >> 24], 1);
        stage2[p] = vv & 0x00FFFFFF;          // src only
    }
    __syncthreads();
    // sorted writeback for agg2
    for (int i = tid; i < len; i += 512) pairs[base + i] = stage2[i];
    // layer-1 aggregation straight from LDS: 2 threads per node
    int t2 = tid >> 1, half = tid & 1;
    int node = nbase + t2;
    if (node >= n) return;
    int beg = ofs[t2], dg = cnt[t2];
    float a0 = 0.f, a1 = 0.f, a2 = 0.f, a3 = 0.f, a4 = 0.f;
    if (!half) {                              // self-loop term
        const float* xo = xs + ((size_t)node << 3);
        a0 = xo[0]; a1 = xo[1]; a2 = xo[2]; a3 = xo[3]; a4 = xo[4];
    }
    for (int e = beg + half; e < beg + dg; e += 2) {
        int s = stage2[e];
        const float* xr = xs + ((size_t)s << 3);
        float4 q = *(const float4*)xr;
        float q4 = xr[4];
        a0 += q.x; a1 += q.y; a2 += q.z; a3 += q.w; a4 += q4;
    }
    a0 += __shfl_xor(a0, 1); a1 += __shfl_xor(a1, 1); a2 += __shfl_xor(a2, 1);
    a3 += __shfl_xor(a3, 1); a4 += __shfl_xor(a4, 1);
    if (half) return;
    float di = dinv[node];
    a0 *= di; a1 *= di; a2 *= di; a3 *= di; a4 *= di;
    float sum = 0.f;
#pragma unroll
    for (int c = 0; c < 32; ++c) {
        float z = bb1[c] + a0 * w1[c] + a1 * w1[32 + c] + a2 * w1[64 + c]
                         + a3 * w1[96 + c] + a4 * w1[128 + c];
        sum += fmaxf(z, 0.f) * w2[c];
    }
    h2s[node] = sum * di;                     // pre-scale by source dinv
}

// ---- layer-2: register accumulation + sigmoid ----
__global__ __launch_bounds__(256) void k_agg2(const int* __restrict__ pairs,
                                              const int* __restrict__ nofs,
                                              const int* __restrict__ deg,
                                              const float* __restrict__ h2s,
                                              const float* __restrict__ dinv,
                                              const float* __restrict__ b2,
                                              float* __restrict__ out, int n) {
    int tid = threadIdx.x;
    int node = blockIdx.x * 128 + (tid >> 1);
    int half = tid & 1;
    if (node >= n) return;
    int beg = nofs[node], dg = deg[node];
    float a = 0.f;
    for (int e = beg + half; e < beg + dg; e += 2) a += h2s[pairs[e]];
    a += __shfl_xor(a, 1);
    if (half) return;
    float v = dinv[node] * (a + h2s[node]) + b2[0];
    out[node] = 1.0f / (1.0f + __expf(-v));
}

extern "C" void kernel_launch(void* const* d_in, const int* in_sizes, int n_in,
                              void* d_out, int out_size, void* d_ws, size_t ws_size,
                              hipStream_t stream) {
    const float* x  = (const float*)d_in[0];
    const int*   ei = (const int*)d_in[1];
    const float* W1 = (const float*)d_in[2];
    const float* b1 = (const float*)d_in[3];
    const float* W2 = (const float*)d_in[4];
    const float* b2 = (const float*)d_in[5];
    float* out = (float*)d_out;

    const int n = in_sizes[0] / 5;       // 100000
    const int E = in_sizes[1] / 2;       // 2500000
    const int* src = ei;
    const int* dst = ei + E;
    const int nb = (n + BNODES - 1) >> NB_SHIFT;   // 391

    // ws (4B units, 16B-aligned):
    // [pairs (nb+1)<<13][nofs n][deg n][dinv n][h2s n][xs 8n][bcur NBK]
    int* wsi = (int*)d_ws;
    int*   pairs = wsi;
    int*   nofs  = wsi + ((size_t)(nb + 1) << CAP_SHIFT);
    int*   deg   = nofs + n;
    float* dinv  = (float*)(deg + n);
    float* h2s   = dinv + n;
    float* xs    = h2s + n;
    int*   bcur  = (int*)(xs + (size_t)8 * n);

    const int nchunk = (E + CHUNK - 1) / CHUNK;    // 512
    const int nagg   = (n + 127) / 128;            // 782

    k_init<<<1, NBK, 0, stream>>>(bcur);
    k_part<<<nchunk, PBLK, 0, stream>>>(src, dst, E, bcur, pairs);
    k_sorta<<<nb, 512, 0, stream>>>(pairs, bcur, x, dinv, xs, nofs, deg, n);
    k_sortagg1<<<nb, 512, 0, stream>>>(pairs, bcur, nofs, deg, xs, dinv,
                                       W1, b1, W2, h2s, n);
    k_agg2<<<nagg, 256, 0, stream>>>(pairs, nofs, deg, h2s, dinv, b2, out, n);
}